// Round 1
// baseline (477.701 us; speedup 1.0000x reference)
//
#include <hip/hip_runtime.h>

// Problem constants (match reference)
#define NO    20000
#define KC    11
#define DIM   256
#define NT    100000
#define OUT_F 128
#define KSEL  10

#define WAVES_PER_BLOCK 4
#define NBLOCKS (NO / WAVES_PER_BLOCK)   // 5000

// ---------------------------------------------------------------------------
// Kernel 1: w2[d] = sum_f W[d,f] * A[OUT_F + f],  d in [0, 2*DIM)
// Collapses the (Cm @ W) @ a2 chain into a single 512-dot per candidate.
// ---------------------------------------------------------------------------
__global__ void compute_w2_kernel(const float* __restrict__ W,
                                  const float* __restrict__ A,
                                  float* __restrict__ w2) {
    int d = blockIdx.x * blockDim.x + threadIdx.x;
    if (d < 2 * DIM) {
        const float* wrow = W + (size_t)d * OUT_F;
        double acc = 0.0;
#pragma unroll 8
        for (int f = 0; f < OUT_F; ++f)
            acc += (double)wrow[f] * (double)A[OUT_F + f];
        w2[d] = (float)acc;
    }
}

// ---------------------------------------------------------------------------
// Kernel 2: one wave per row n.
//  - e[k] = Candidate[n,k,:].w2[:256] + data_m_train[ni[n,k],:].w2[256:]
//    (eX is constant over k -> irrelevant to selection -> skipped entirely)
//  - drop = argmin_k e[k] (tie: drop last tied index, matches lax.top_k)
//  - write the 10 surviving candidate rows / nd / ni; accumulate dmc sums.
// ---------------------------------------------------------------------------
__global__ __launch_bounds__(WAVES_PER_BLOCK * 64)
void select_kernel(const float* __restrict__ Cand,
                   const float* __restrict__ nd_in,
                   const int*   __restrict__ ni_in,
                   const float* __restrict__ dtrain,
                   const float* __restrict__ w2,
                   float* __restrict__ outC,
                   float* __restrict__ outND,
                   float* __restrict__ outNI,
                   double* __restrict__ partA,
                   double* __restrict__ partB) {
    const int lane = threadIdx.x & 63;
    const int wv   = threadIdx.x >> 6;
    const int n    = blockIdx.x * WAVES_PER_BLOCK + wv;   // grid exactly covers NO

    // Per-lane slice of w2 (first 256 = candidate part, last 256 = dmc part)
    const float4 w2a = *(const float4*)(w2 + lane * 4);
    const float4 w2b = *(const float4*)(w2 + 256 + lane * 4);

    // Load all 11 candidate rows into registers (read Candidate exactly once)
    const float* crow = Cand + ((size_t)n * KC) * DIM + lane * 4;
    float4 c[KC];
#pragma unroll
    for (int k = 0; k < KC; ++k)
        c[k] = *(const float4*)(crow + k * DIM);

    // neigh_ind for this row (wave-uniform loads)
    int inds[KC];
#pragma unroll
    for (int k = 0; k < KC; ++k)
        inds[k] = ni_in[n * KC + k];

    double e[KC];
    float  s[KC];
#pragma unroll
    for (int k = 0; k < KC; ++k) {
        const float4 m = *(const float4*)(dtrain + (size_t)inds[k] * DIM + lane * 4);
        double dot = (double)c[k].x * w2a.x + (double)c[k].y * w2a.y
                   + (double)c[k].z * w2a.z + (double)c[k].w * w2a.w
                   + (double)m.x * w2b.x + (double)m.y * w2b.y
                   + (double)m.z * w2b.z + (double)m.w * w2b.w;
        float sum = m.x + m.y + m.z + m.w;
        // Butterfly reduce -> bitwise-identical result on every lane
#pragma unroll
        for (int off = 32; off; off >>= 1) {
            dot += __shfl_xor(dot, off, 64);
            sum += __shfl_xor(sum, off, 64);
        }
        e[k] = dot;
        s[k] = sum;
    }

    // argmin with "drop the last tied index" (top_k keeps lower index on ties)
    double mine  = e[0];
    int    drop  = 0;
    float  sdrop = s[0];
    float  stot  = s[0];
#pragma unroll
    for (int k = 1; k < KC; ++k) {
        stot += s[k];
        if (e[k] <= mine) { mine = e[k]; drop = k; sdrop = s[k]; }
    }

    // Write the 10 surviving candidate rows (static register selects, coalesced)
    const size_t ob = (size_t)n * KSEL * DIM + lane * 4;
#pragma unroll
    for (int j = 0; j < KSEL; ++j) {
        const float4 v = (j >= drop) ? c[j + 1] : c[j];
        *(float4*)(outC + ob + (size_t)j * DIM) = v;
    }

    // nd / ni gathers (ni stored as float; exact for values < 2^24)
    if (lane < KSEL) {
        const int src = lane + (lane >= drop ? 1 : 0);
        outND[n * KSEL + lane] = nd_in[n * KC + src];
        outNI[n * KSEL + lane] = (float)ni_in[n * KC + src];
    }

    // Deterministic per-block partial sums for a_out / b_out
    __shared__ float shA[WAVES_PER_BLOCK], shB[WAVES_PER_BLOCK];
    if (lane == 0) { shA[wv] = stot - sdrop; shB[wv] = sdrop; }
    __syncthreads();
    if (threadIdx.x == 0) {
        float a = 0.f, b = 0.f;
#pragma unroll
        for (int w = 0; w < WAVES_PER_BLOCK; ++w) { a += shA[w]; b += shB[w]; }
        partA[blockIdx.x] = (double)a;
        partB[blockIdx.x] = (double)b;
    }
}

// ---------------------------------------------------------------------------
// Kernel 3: reduce the 5000 block partials -> a_out, b_out
// ---------------------------------------------------------------------------
__global__ void finalize_kernel(const double* __restrict__ partA,
                                const double* __restrict__ partB,
                                float* __restrict__ outA,
                                float* __restrict__ outB) {
    __shared__ double sA[256], sB[256];
    double a = 0.0, b = 0.0;
    for (int i = threadIdx.x; i < NBLOCKS; i += 256) {
        a += partA[i];
        b += partB[i];
    }
    sA[threadIdx.x] = a;
    sB[threadIdx.x] = b;
    __syncthreads();
    for (int s = 128; s; s >>= 1) {
        if (threadIdx.x < s) {
            sA[threadIdx.x] += sA[threadIdx.x + s];
            sB[threadIdx.x] += sB[threadIdx.x + s];
        }
        __syncthreads();
    }
    if (threadIdx.x == 0) {
        *outA = (float)(sA[0] / (double)((size_t)NO * KSEL));
        *outB = (float)(sB[0] / (double)NO);
    }
}

extern "C" void kernel_launch(void* const* d_in, const int* in_sizes, int n_in,
                              void* d_out, int out_size, void* d_ws, size_t ws_size,
                              hipStream_t stream) {
    // Input order: X, Candidate, neigh_dist, neigh_ind, data_m_train,
    //              data_m_batch, test, W, A
    const float* Cand   = (const float*)d_in[1];
    const float* ndist  = (const float*)d_in[2];
    const int*   nind   = (const int*)d_in[3];
    const float* dtrain = (const float*)d_in[4];
    const float* W      = (const float*)d_in[7];
    const float* A      = (const float*)d_in[8];

    float* out   = (float*)d_out;
    float* outC  = out;                                   // [NO, KSEL, DIM]
    float* outND = out + (size_t)NO * KSEL * DIM;         // [NO, KSEL]
    float* outNI = outND + (size_t)NO * KSEL;             // [NO, KSEL] (as f32)
    float* outA  = outNI + (size_t)NO * KSEL;             // scalar
    float* outB  = outA + 1;                              // scalar

    // Workspace layout: w2 (512 f32) @0, block partials (2 x 5000 f64) @4096
    float*  w2    = (float*)d_ws;
    double* partA = (double*)((char*)d_ws + 4096);
    double* partB = partA + NBLOCKS;

    compute_w2_kernel<<<2, 256, 0, stream>>>(W, A, w2);
    select_kernel<<<NBLOCKS, WAVES_PER_BLOCK * 64, 0, stream>>>(
        Cand, ndist, nind, dtrain, w2, outC, outND, outNI, partA, partB);
    finalize_kernel<<<1, 256, 0, stream>>>(partA, partB, outA, outB);
}

// Round 2
// 477.237 us; speedup vs baseline: 1.0010x; 1.0010x over previous
//
#include <hip/hip_runtime.h>

// Problem constants (match reference)
#define NO    20000
#define KC    11
#define DIM   256
#define NT    100000
#define OUT_F 128
#define KSEL  10

#define WAVES_PER_BLOCK 4
#define NBLOCKS (NO / WAVES_PER_BLOCK)   // 5000

// ---------------------------------------------------------------------------
// Kernel 1: w2[d] = sum_f W[d,f] * A[OUT_F + f],  d in [0, 2*DIM)
// ---------------------------------------------------------------------------
__global__ void compute_w2_kernel(const float* __restrict__ W,
                                  const float* __restrict__ A,
                                  float* __restrict__ w2) {
    int d = blockIdx.x * blockDim.x + threadIdx.x;
    if (d < 2 * DIM) {
        const float* wrow = W + (size_t)d * OUT_F;
        double a0 = 0.0, a1 = 0.0, a2 = 0.0, a3 = 0.0;
#pragma unroll 8
        for (int f = 0; f < OUT_F; f += 4) {
            a0 += (double)wrow[f + 0] * (double)A[OUT_F + f + 0];
            a1 += (double)wrow[f + 1] * (double)A[OUT_F + f + 1];
            a2 += (double)wrow[f + 2] * (double)A[OUT_F + f + 2];
            a3 += (double)wrow[f + 3] * (double)A[OUT_F + f + 3];
        }
        w2[d] = (float)((a0 + a1) + (a2 + a3));
    }
}

// ---------------------------------------------------------------------------
// Kernel 2: one wave per row n.
// launch_bounds(256,3): VGPR cap ~168 so all 22 loads (11 candidate float4 +
// 11 gather float4) stay in flight simultaneously. R1's 64-VGPR version
// serialized the gathers (one m-register reused per k) -> latency-bound at
// 46% of achievable HBM BW.
// ---------------------------------------------------------------------------
__global__ __launch_bounds__(WAVES_PER_BLOCK * 64, 3)
void select_kernel(const float* __restrict__ Cand,
                   const float* __restrict__ nd_in,
                   const int*   __restrict__ ni_in,
                   const float* __restrict__ dtrain,
                   const float* __restrict__ w2,
                   float* __restrict__ outC,
                   float* __restrict__ outND,
                   float* __restrict__ outNI,
                   double* __restrict__ partA,
                   double* __restrict__ partB) {
    const int lane = threadIdx.x & 63;
    const int wv   = threadIdx.x >> 6;
    const int n    = blockIdx.x * WAVES_PER_BLOCK + wv;   // grid exactly covers NO

    // Per-lane slice of w2 (first 256 = candidate part, last 256 = dmc part)
    const float4 w2a = *(const float4*)(w2 + lane * 4);
    const float4 w2b = *(const float4*)(w2 + 256 + lane * 4);

    // 1) wave-uniform neighbor indices (issue first; m-addresses depend on them)
    int inds[KC];
#pragma unroll
    for (int k = 0; k < KC; ++k)
        inds[k] = ni_in[n * KC + k];

    // 2) all 11 candidate rows -> registers (held until the store phase)
    const float* crow = Cand + ((size_t)n * KC) * DIM + lane * 4;
    float4 c[KC];
#pragma unroll
    for (int k = 0; k < KC; ++k)
        c[k] = *(const float4*)(crow + k * DIM);

    // 3) all 11 gather rows -> registers (full MLP: 22 loads in flight)
    float4 m[KC];
#pragma unroll
    for (int k = 0; k < KC; ++k)
        m[k] = *(const float4*)(dtrain + (size_t)inds[k] * DIM + lane * 4);

    // 4) per-lane partial scores (f64 for exact selection match) and row sums
    double e[KC];
    float  ps[KC];
    float  stp = 0.f;
#pragma unroll
    for (int k = 0; k < KC; ++k) {
        e[k] = (double)c[k].x * w2a.x + (double)c[k].y * w2a.y
             + (double)c[k].z * w2a.z + (double)c[k].w * w2a.w
             + (double)m[k].x * w2b.x + (double)m[k].y * w2b.y
             + (double)m[k].z * w2b.z + (double)m[k].w * w2b.w;
        ps[k] = (m[k].x + m[k].y) + (m[k].z + m[k].w);
        stp  += ps[k];
    }

    // 5) stage-major butterfly: 11 independent chains overlap per stage
#pragma unroll
    for (int off = 32; off; off >>= 1) {
#pragma unroll
        for (int k = 0; k < KC; ++k)
            e[k] += __shfl_xor(e[k], off, 64);
    }

    // 6) argmin with "drop the last tied index" (top_k keeps lower index on ties)
    double mine = e[0];
    int    drop = 0;
#pragma unroll
    for (int k = 1; k < KC; ++k)
        if (e[k] <= mine) { mine = e[k]; drop = k; }

    // 7) only 2 sum reductions needed: total and the dropped row
    float sd = ps[0];
#pragma unroll
    for (int k = 1; k < KC; ++k)
        sd = (drop == k) ? ps[k] : sd;
#pragma unroll
    for (int off = 32; off; off >>= 1) {
        stp += __shfl_xor(stp, off, 64);
        sd  += __shfl_xor(sd,  off, 64);
    }

    // 8) write the 10 surviving candidate rows (static register selects)
    const size_t ob = (size_t)n * KSEL * DIM + lane * 4;
#pragma unroll
    for (int j = 0; j < KSEL; ++j) {
        const float4 v = (j >= drop) ? c[j + 1] : c[j];
        *(float4*)(outC + ob + (size_t)j * DIM) = v;
    }

    // nd / ni gathers (ni stored as float; exact for values < 2^24)
    if (lane < KSEL) {
        const int src = lane + (lane >= drop ? 1 : 0);
        outND[n * KSEL + lane] = nd_in[n * KC + src];
        outNI[n * KSEL + lane] = (float)ni_in[n * KC + src];
    }

    // Deterministic per-block partial sums for a_out / b_out
    __shared__ float shA[WAVES_PER_BLOCK], shB[WAVES_PER_BLOCK];
    if (lane == 0) { shA[wv] = stp - sd; shB[wv] = sd; }
    __syncthreads();
    if (threadIdx.x == 0) {
        float a = 0.f, b = 0.f;
#pragma unroll
        for (int w = 0; w < WAVES_PER_BLOCK; ++w) { a += shA[w]; b += shB[w]; }
        partA[blockIdx.x] = (double)a;
        partB[blockIdx.x] = (double)b;
    }
}

// ---------------------------------------------------------------------------
// Kernel 3: reduce the 5000 block partials -> a_out, b_out
// ---------------------------------------------------------------------------
__global__ void finalize_kernel(const double* __restrict__ partA,
                                const double* __restrict__ partB,
                                float* __restrict__ outA,
                                float* __restrict__ outB) {
    __shared__ double sA[256], sB[256];
    double a = 0.0, b = 0.0;
    for (int i = threadIdx.x; i < NBLOCKS; i += 256) {
        a += partA[i];
        b += partB[i];
    }
    sA[threadIdx.x] = a;
    sB[threadIdx.x] = b;
    __syncthreads();
    for (int s = 128; s; s >>= 1) {
        if (threadIdx.x < s) {
            sA[threadIdx.x] += sA[threadIdx.x + s];
            sB[threadIdx.x] += sB[threadIdx.x + s];
        }
        __syncthreads();
    }
    if (threadIdx.x == 0) {
        *outA = (float)(sA[0] / (double)((size_t)NO * KSEL));
        *outB = (float)(sB[0] / (double)NO);
    }
}

extern "C" void kernel_launch(void* const* d_in, const int* in_sizes, int n_in,
                              void* d_out, int out_size, void* d_ws, size_t ws_size,
                              hipStream_t stream) {
    // Input order: X, Candidate, neigh_dist, neigh_ind, data_m_train,
    //              data_m_batch, test, W, A
    const float* Cand   = (const float*)d_in[1];
    const float* ndist  = (const float*)d_in[2];
    const int*   nind   = (const int*)d_in[3];
    const float* dtrain = (const float*)d_in[4];
    const float* W      = (const float*)d_in[7];
    const float* A      = (const float*)d_in[8];

    float* out   = (float*)d_out;
    float* outC  = out;                                   // [NO, KSEL, DIM]
    float* outND = out + (size_t)NO * KSEL * DIM;         // [NO, KSEL]
    float* outNI = outND + (size_t)NO * KSEL;             // [NO, KSEL] (as f32)
    float* outA  = outNI + (size_t)NO * KSEL;             // scalar
    float* outB  = outA + 1;                              // scalar

    // Workspace layout: w2 (512 f32) @0, block partials (2 x 5000 f64) @4096
    float*  w2    = (float*)d_ws;
    double* partA = (double*)((char*)d_ws + 4096);
    double* partB = partA + NBLOCKS;

    compute_w2_kernel<<<2, 256, 0, stream>>>(W, A, w2);
    select_kernel<<<NBLOCKS, WAVES_PER_BLOCK * 64, 0, stream>>>(
        Cand, ndist, nind, dtrain, w2, outC, outND, outNI, partA, partB);
    finalize_kernel<<<1, 256, 0, stream>>>(partA, partB, outA, outB);
}